// Round 6
// baseline (451.113 us; speedup 1.0000x reference)
//
#include <hip/hip_runtime.h>

#define N_NODES 50000
#define N_EDGES 800000
#define NFEAT 512
#define NHID 128
#define NCLASS 64

#define SCAN_BLOCKS 49   // ceil(50000/1024)
#define RPB 128          // rows per bucket
#define NBUCK 391        // ceil(50000/128)

using bf16x8 = __attribute__((ext_vector_type(8))) __bf16;
using f32x4  = __attribute__((ext_vector_type(4))) float;
using u16x8  = __attribute__((ext_vector_type(8))) unsigned short;
using u16x4  = __attribute__((ext_vector_type(4))) unsigned short;
typedef unsigned long long u64;

__device__ __forceinline__ unsigned short f2bf(float f)
{
    unsigned u = __builtin_bit_cast(unsigned, f);
    unsigned r = (u + 0x7FFFu + ((u >> 16) & 1u)) >> 16;
    return (unsigned short)r;
}
__device__ __forceinline__ float bf2f(unsigned short b)
{
    return __builtin_bit_cast(float, (unsigned)b << 16);
}

// ---------------- both weights transpose + bf16 convert, one launch ----------
__global__ void convert_weights(const float* __restrict__ W1, const float* __restrict__ W2,
                                unsigned short* __restrict__ W1t, unsigned short* __restrict__ W2t)
{
    int idx = blockIdx.x * blockDim.x + threadIdx.x;
    if (idx < NFEAT * NHID) {
        int n = idx / NFEAT, k = idx % NFEAT;
        W1t[idx] = f2bf(W1[k * NHID + n]);
    } else {
        int j = idx - NFEAT * NHID;
        if (j < NHID * NCLASS) {
            int n = j / NHID, k = j % NHID;
            W2t[j] = f2bf(W2[k * NCLASS + n]);
        }
    }
}

// ------------- MFMA GEMM, fp32 A (rounded to bf16), bf16 out -----------------
template<int K, int N>
__global__ __launch_bounds__(256) void gemm_mfma_f32a(const float* __restrict__ A,
                                                      const unsigned short* __restrict__ Bt,
                                                      unsigned short* __restrict__ C, int M)
{
    constexpr int BM = 128, BK = 32, NF = N / 16;
    constexpr int LDW = BK + 8;  // row stride 80 B -> <=2-way bank conflicts (free)
    __shared__ unsigned short As[BM][LDW];
    __shared__ unsigned short Bs[N][LDW];

    const int tid  = threadIdx.x;
    const int wid  = tid >> 6;
    const int lane = tid & 63;
    const int lm   = lane & 15;
    const int lk   = (lane >> 4) * 8;
    const int m0   = blockIdx.x * BM;

    f32x4 acc[2][NF] = {};

    for (int k0 = 0; k0 < K; k0 += BK) {
        if (k0) __syncthreads();
        {
            const int r  = tid >> 1;
            const int kc = (tid & 1) * 16;
            const int m  = m0 + r;
            #pragma unroll
            for (int c = 0; c < 4; ++c) {
                float4 f = make_float4(0.f, 0.f, 0.f, 0.f);
                if (m < M) f = *(const float4*)&A[(size_t)m * K + k0 + kc + c * 4];
                u16x4 h;
                h[0] = f2bf(f.x); h[1] = f2bf(f.y); h[2] = f2bf(f.z); h[3] = f2bf(f.w);
                *(u16x4*)&As[r][kc + c * 4] = h;
            }
        }
        {
            constexpr int CH  = (N * BK / 8) / 256;
            constexpr int CPR = BK / 8;
            #pragma unroll
            for (int c = 0; c < CH; ++c) {
                const int chunk = tid * CH + c;
                const int n  = chunk / CPR;
                const int kc = (chunk % CPR) * 8;
                *(u16x8*)&Bs[n][kc] = *(const u16x8*)&Bt[(size_t)n * K + k0 + kc];
            }
        }
        __syncthreads();

        bf16x8 a[2];
        #pragma unroll
        for (int mf = 0; mf < 2; ++mf)
            a[mf] = __builtin_bit_cast(bf16x8, *(const u16x8*)&As[wid * 32 + mf * 16 + lm][lk]);
        #pragma unroll
        for (int nf = 0; nf < NF; ++nf) {
            bf16x8 b = __builtin_bit_cast(bf16x8, *(const u16x8*)&Bs[nf * 16 + lm][lk]);
            #pragma unroll
            for (int mf = 0; mf < 2; ++mf)
                acc[mf][nf] = __builtin_amdgcn_mfma_f32_16x16x32_bf16(a[mf], b, acc[mf][nf], 0, 0, 0);
        }
    }

    #pragma unroll
    for (int mf = 0; mf < 2; ++mf)
        #pragma unroll
        for (int nf = 0; nf < NF; ++nf)
            #pragma unroll
            for (int r = 0; r < 4; ++r) {
                const int m = m0 + wid * 32 + mf * 16 + (lane >> 4) * 4 + r;
                if (m < M) C[(size_t)m * N + nf * 16 + lm] = f2bf(acc[mf][nf][r]);
            }
}

// ------------- MFMA GEMM, bf16 A, bf16 out -----------------------------------
template<int K, int N>
__global__ __launch_bounds__(256) void gemm_mfma_bf16a(const unsigned short* __restrict__ A,
                                                       const unsigned short* __restrict__ Bt,
                                                       unsigned short* __restrict__ C, int M)
{
    constexpr int BM = 128, BK = 32, NF = N / 16;
    constexpr int LDW = BK + 8;
    __shared__ unsigned short As[BM][LDW];
    __shared__ unsigned short Bs[N][LDW];

    const int tid  = threadIdx.x;
    const int wid  = tid >> 6;
    const int lane = tid & 63;
    const int lm   = lane & 15;
    const int lk   = (lane >> 4) * 8;
    const int m0   = blockIdx.x * BM;

    f32x4 acc[2][NF] = {};

    for (int k0 = 0; k0 < K; k0 += BK) {
        if (k0) __syncthreads();
        {
            #pragma unroll
            for (int c = 0; c < 2; ++c) {
                const int chunk = tid * 2 + c;     // 512 chunks
                const int r  = chunk >> 2;
                const int kc = (chunk & 3) * 8;
                const int m  = m0 + r;
                u16x8 v = {};
                if (m < M) v = *(const u16x8*)&A[(size_t)m * K + k0 + kc];
                *(u16x8*)&As[r][kc] = v;
            }
        }
        {
            constexpr int CH  = (N * BK / 8) / 256;   // N=64 -> 1
            constexpr int CPR = BK / 8;
            #pragma unroll
            for (int c = 0; c < CH; ++c) {
                const int chunk = tid * CH + c;
                const int n  = chunk / CPR;
                const int kc = (chunk % CPR) * 8;
                *(u16x8*)&Bs[n][kc] = *(const u16x8*)&Bt[(size_t)n * K + k0 + kc];
            }
        }
        __syncthreads();

        bf16x8 a[2];
        #pragma unroll
        for (int mf = 0; mf < 2; ++mf)
            a[mf] = __builtin_bit_cast(bf16x8, *(const u16x8*)&As[wid * 32 + mf * 16 + lm][lk]);
        #pragma unroll
        for (int nf = 0; nf < NF; ++nf) {
            bf16x8 b = __builtin_bit_cast(bf16x8, *(const u16x8*)&Bs[nf * 16 + lm][lk]);
            #pragma unroll
            for (int mf = 0; mf < 2; ++mf)
                acc[mf][nf] = __builtin_amdgcn_mfma_f32_16x16x32_bf16(a[mf], b, acc[mf][nf], 0, 0, 0);
        }
    }

    #pragma unroll
    for (int mf = 0; mf < 2; ++mf)
        #pragma unroll
        for (int nf = 0; nf < NF; ++nf)
            #pragma unroll
            for (int r = 0; r < 4; ++r) {
                const int m = m0 + wid * 32 + mf * 16 + (lane >> 4) * 4 + r;
                if (m < M) C[(size_t)m * N + nf * 16 + lm] = f2bf(acc[mf][nf][r]);
            }
}

// ---------------- CSR build ----------------
__global__ void hist_kernel(const int* __restrict__ er, int* __restrict__ counts)
{
    int e = blockIdx.x * blockDim.x + threadIdx.x;
    if (e < N_EDGES) atomicAdd(&counts[er[e]], 1);
}

__global__ __launch_bounds__(1024) void scan_blocks(const int* __restrict__ counts,
                                                    int* __restrict__ row_ptr,
                                                    int* __restrict__ bsums)
{
    __shared__ int tmp[1024];
    const int tid = threadIdx.x;
    const int gid = blockIdx.x * 1024 + tid;
    const int v = (gid < N_NODES) ? counts[gid] : 0;
    tmp[tid] = v;
    __syncthreads();
    #pragma unroll
    for (int off = 1; off < 1024; off <<= 1) {
        int t = (tid >= off) ? tmp[tid - off] : 0;
        __syncthreads();
        tmp[tid] += t;
        __syncthreads();
    }
    if (gid < N_NODES) row_ptr[gid] = tmp[tid] - v;
    if (tid == 1023) bsums[blockIdx.x] = tmp[1023];
}

__global__ void scan_bsums(int* __restrict__ bsums)
{
    const int lane = threadIdx.x;  // 64 threads
    const int orig = (lane < SCAN_BLOCKS) ? bsums[lane] : 0;
    int v = orig;
    #pragma unroll
    for (int off = 1; off < 64; off <<= 1) {
        int t = __shfl_up(v, off, 64);
        if (lane >= off) v += t;
    }
    if (lane < SCAN_BLOCKS) bsums[lane] = v - orig;  // exclusive
}

__global__ __launch_bounds__(1024) void add_offsets(int* __restrict__ row_ptr,
                                                    const int* __restrict__ bsums)
{
    const int gid = blockIdx.x * 1024 + threadIdx.x;
    if (gid < N_NODES) row_ptr[gid] += bsums[blockIdx.x];
    if (gid == 0) row_ptr[N_NODES] = N_EDGES;
}

// ---- Phase A: bucket scatter. tmp[pos] = {val:32 | col:16 | localrow:7} -----
__global__ void bucket_scatter(const int* __restrict__ er, const int* __restrict__ ec,
                               const float* __restrict__ ev,
                               const int* __restrict__ row_ptr, int* __restrict__ bfill,
                               u64* __restrict__ tmp)
{
    int e = blockIdx.x * blockDim.x + threadIdx.x;
    if (e >= N_EDGES) return;
    const int r = er[e];
    const int b = r >> 7;
    const int base = row_ptr[b << 7];          // bucket region base in CSR order
    const int pos = base + atomicAdd(&bfill[b], 1);
    const u64 p = ((u64)__builtin_bit_cast(unsigned, ev[e]) << 32)
                | ((unsigned)ec[e] << 7) | (unsigned)(r & (RPB - 1));
    tmp[pos] = p;
}

// ---- Phase B: within-bucket sort into final packed CSR {val:32 | col:32} ----
__global__ __launch_bounds__(256) void bucket_sort(const u64* __restrict__ tmp,
                                                   const int* __restrict__ row_ptr,
                                                   u64* __restrict__ cv)
{
    __shared__ int rp[RPB];
    __shared__ int lfill[RPB];
    const int b = blockIdx.x;
    const int t = threadIdx.x;
    const int r0 = b << 7;
    if (t < RPB) {
        const int r = r0 + t;
        rp[t] = (r < N_NODES) ? row_ptr[r] : N_EDGES;
        lfill[t] = 0;
    }
    __syncthreads();
    const int beg = row_ptr[r0];
    const int rend = (r0 + RPB < N_NODES) ? (r0 + RPB) : N_NODES;
    const int end = row_ptr[rend];
    for (int i = beg + t; i < end; i += 256) {
        const u64 p = tmp[i];
        const int lr  = (int)(p & (RPB - 1));
        const int col = (int)((p >> 7) & 0xFFFFu);
        const unsigned vb = (unsigned)(p >> 32);
        const int pos = rp[lr] + atomicAdd(&lfill[lr], 1);
        cv[pos] = ((u64)vb << 32) | (unsigned)col;
    }
}

// ---- SpMM1: bf16 feat [*,128] gather, fp32 acc, +bias, relu, bf16 out -------
__global__ __launch_bounds__(256) void spmm_bf16_h(const unsigned short* __restrict__ feat,
                                                   const int* __restrict__ row_ptr,
                                                   const u64* __restrict__ cv,
                                                   const float* __restrict__ bias,
                                                   unsigned short* __restrict__ out)
{
    const int wave = blockIdx.x * (blockDim.x >> 6) + (threadIdx.x >> 6);
    const int lane = threadIdx.x & 63;
    if (wave >= N_NODES) return;
    const int beg = row_ptr[wave];
    const int end = row_ptr[wave + 1];

    float ax[4] = {}, ay[4] = {};
    int i = beg;
    for (; i + 3 < end; i += 4) {
        #pragma unroll
        for (int u = 0; u < 4; ++u) {
            const u64 p = cv[i + u];
            const int c = (int)(unsigned)p;
            const float v = __builtin_bit_cast(float, (unsigned)(p >> 32));
            const unsigned w = *(const unsigned*)&feat[(size_t)c * NHID + lane * 2];
            ax[u] += v * bf2f((unsigned short)(w & 0xFFFF));
            ay[u] += v * bf2f((unsigned short)(w >> 16));
        }
    }
    for (; i < end; ++i) {
        const u64 p = cv[i];
        const int c = (int)(unsigned)p;
        const float v = __builtin_bit_cast(float, (unsigned)(p >> 32));
        const unsigned w = *(const unsigned*)&feat[(size_t)c * NHID + lane * 2];
        ax[0] += v * bf2f((unsigned short)(w & 0xFFFF));
        ay[0] += v * bf2f((unsigned short)(w >> 16));
    }
    const float2 bb = *(const float2*)&bias[lane * 2];
    const float rx = fmaxf(ax[0] + ax[1] + ax[2] + ax[3] + bb.x, 0.f);
    const float ry = fmaxf(ay[0] + ay[1] + ay[2] + ay[3] + bb.y, 0.f);
    const unsigned pack = (unsigned)f2bf(rx) | ((unsigned)f2bf(ry) << 16);
    *(unsigned*)&out[(size_t)wave * NHID + lane * 2] = pack;
}

// ---- SpMM2: bf16 feat [*,64] gather, fp32 acc, +bias, fp32 out --------------
__global__ __launch_bounds__(256) void spmm_bf16_o(const unsigned short* __restrict__ feat,
                                                   const int* __restrict__ row_ptr,
                                                   const u64* __restrict__ cv,
                                                   const float* __restrict__ bias,
                                                   float* __restrict__ out)
{
    const int wave = blockIdx.x * (blockDim.x >> 6) + (threadIdx.x >> 6);
    const int lane = threadIdx.x & 63;
    if (wave >= N_NODES) return;
    const int beg = row_ptr[wave];
    const int end = row_ptr[wave + 1];

    float a[4] = {};
    int i = beg;
    for (; i + 3 < end; i += 4) {
        #pragma unroll
        for (int u = 0; u < 4; ++u) {
            const u64 p = cv[i + u];
            const int c = (int)(unsigned)p;
            const float v = __builtin_bit_cast(float, (unsigned)(p >> 32));
            a[u] += v * bf2f(feat[(size_t)c * NCLASS + lane]);
        }
    }
    for (; i < end; ++i) {
        const u64 p = cv[i];
        const int c = (int)(unsigned)p;
        const float v = __builtin_bit_cast(float, (unsigned)(p >> 32));
        a[0] += v * bf2f(feat[(size_t)c * NCLASS + lane]);
    }
    out[(size_t)wave * NCLASS + lane] = a[0] + a[1] + a[2] + a[3] + bias[lane];
}

extern "C" void kernel_launch(void* const* d_in, const int* in_sizes, int n_in,
                              void* d_out, int out_size, void* d_ws, size_t ws_size,
                              hipStream_t stream)
{
    const float* x  = (const float*)d_in[0];
    const float* W1 = (const float*)d_in[1];
    const float* b1 = (const float*)d_in[2];
    const float* W2 = (const float*)d_in[3];
    const float* b2 = (const float*)d_in[4];
    const float* ev = (const float*)d_in[5];
    const int*   er = (const int*)d_in[6];
    const int*   ec = (const int*)d_in[7];
    float* out = (float*)d_out;

    // ---- workspace layout (8B-aligned things first) ----
    u64* tmp = (u64*)d_ws;                                   // 800,000 u64
    u64* cv  = tmp + N_EDGES;                                // 800,000 u64
    unsigned short* XW1  = (unsigned short*)(cv + N_EDGES);  // 6,400,000 u16
    unsigned short* Hpre = XW1 + (size_t)N_NODES * NHID;     // 6,400,000 u16
    int* row_ptr = (int*)(Hpre + (size_t)N_NODES * NHID);    // 50016
    int* counts  = row_ptr + 50016;                          // 50016
    int* bsums   = counts + 50016;                           // 64
    int* bfill   = bsums + 64;                               // 512
    unsigned short* W1t = (unsigned short*)(bfill + 512);    // 65536 u16
    unsigned short* W2t = W1t + NFEAT * NHID;                // 8192 u16

    unsigned short* HW2 = XW1;  // [N_NODES, NCLASS] bf16, reuses XW1 slot

    // ---- CSR build ----
    hipMemsetAsync(counts, 0, (50016 + 64 + 512) * sizeof(int), stream);  // counts,bsums,bfill
    hist_kernel<<<(N_EDGES + 255) / 256, 256, 0, stream>>>(er, counts);
    scan_blocks<<<SCAN_BLOCKS, 1024, 0, stream>>>(counts, row_ptr, bsums);
    scan_bsums<<<1, 64, 0, stream>>>(bsums);
    add_offsets<<<SCAN_BLOCKS, 1024, 0, stream>>>(row_ptr, bsums);
    bucket_scatter<<<(N_EDGES + 255) / 256, 256, 0, stream>>>(er, ec, ev, row_ptr, bfill, tmp);
    bucket_sort<<<NBUCK, 256, 0, stream>>>(tmp, row_ptr, cv);

    // ---- weight preconvert (bf16, transposed), one launch ----
    {
        const int total = NFEAT * NHID + NHID * NCLASS;
        convert_weights<<<(total + 255) / 256, 256, 0, stream>>>(W1, W2, W1t, W2t);
    }

    // ---- layer 1 ----
    gemm_mfma_f32a<NFEAT, NHID><<<(N_NODES + 127) / 128, 256, 0, stream>>>(x, W1t, XW1, N_NODES);
    spmm_bf16_h<<<(N_NODES + 3) / 4, 256, 0, stream>>>(XW1, row_ptr, cv, b1, Hpre);
    // ---- layer 2 ----
    gemm_mfma_bf16a<NHID, NCLASS><<<(N_NODES + 127) / 128, 256, 0, stream>>>(Hpre, W2t, HW2, N_NODES);
    spmm_bf16_o<<<(N_NODES + 3) / 4, 256, 0, stream>>>(HW2, row_ptr, cv, b2, out);
}

// Round 7
// 205.954 us; speedup vs baseline: 2.1904x; 2.1904x over previous
//
#include <hip/hip_runtime.h>

#define N_NODES 50000
#define N_EDGES 800000
#define NFEAT 512
#define NHID 128
#define NCLASS 64

#define SCAN_BLOCKS 49   // ceil(50000/1024)

using bf16x8 = __attribute__((ext_vector_type(8))) __bf16;
using f32x4  = __attribute__((ext_vector_type(4))) float;
using u16x8  = __attribute__((ext_vector_type(8))) unsigned short;
using u16x4  = __attribute__((ext_vector_type(4))) unsigned short;
typedef unsigned long long u64;

__device__ __forceinline__ unsigned short f2bf(float f)
{
    unsigned u = __builtin_bit_cast(unsigned, f);
    unsigned r = (u + 0x7FFFu + ((u >> 16) & 1u)) >> 16;
    return (unsigned short)r;
}
__device__ __forceinline__ float bf2f(unsigned short b)
{
    return __builtin_bit_cast(float, (unsigned)b << 16);
}

// ---------------- both weights transpose + bf16 convert, one launch ----------
__global__ void convert_weights(const float* __restrict__ W1, const float* __restrict__ W2,
                                unsigned short* __restrict__ W1t, unsigned short* __restrict__ W2t)
{
    int idx = blockIdx.x * blockDim.x + threadIdx.x;
    if (idx < NFEAT * NHID) {
        int n = idx / NFEAT, k = idx % NFEAT;
        W1t[idx] = f2bf(W1[k * NHID + n]);
    } else {
        int j = idx - NFEAT * NHID;
        if (j < NHID * NCLASS) {
            int n = j / NHID, k = j % NHID;
            W2t[j] = f2bf(W2[k * NCLASS + n]);
        }
    }
}

// ------------- MFMA GEMM, fp32 A (rounded to bf16), bf16 out -----------------
template<int K, int N>
__global__ __launch_bounds__(256) void gemm_mfma_f32a(const float* __restrict__ A,
                                                      const unsigned short* __restrict__ Bt,
                                                      unsigned short* __restrict__ C, int M)
{
    constexpr int BM = 128, BK = 32, NF = N / 16;
    constexpr int LDW = BK + 8;  // row stride 80 B -> <=2-way bank conflicts (free)
    __shared__ unsigned short As[BM][LDW];
    __shared__ unsigned short Bs[N][LDW];

    const int tid  = threadIdx.x;
    const int wid  = tid >> 6;
    const int lane = tid & 63;
    const int lm   = lane & 15;
    const int lk   = (lane >> 4) * 8;
    const int m0   = blockIdx.x * BM;

    f32x4 acc[2][NF] = {};

    for (int k0 = 0; k0 < K; k0 += BK) {
        if (k0) __syncthreads();
        {
            const int r  = tid >> 1;
            const int kc = (tid & 1) * 16;
            const int m  = m0 + r;
            #pragma unroll
            for (int c = 0; c < 4; ++c) {
                float4 f = make_float4(0.f, 0.f, 0.f, 0.f);
                if (m < M) f = *(const float4*)&A[(size_t)m * K + k0 + kc + c * 4];
                u16x4 h;
                h[0] = f2bf(f.x); h[1] = f2bf(f.y); h[2] = f2bf(f.z); h[3] = f2bf(f.w);
                *(u16x4*)&As[r][kc + c * 4] = h;
            }
        }
        {
            constexpr int CH  = (N * BK / 8) / 256;
            constexpr int CPR = BK / 8;
            #pragma unroll
            for (int c = 0; c < CH; ++c) {
                const int chunk = tid * CH + c;
                const int n  = chunk / CPR;
                const int kc = (chunk % CPR) * 8;
                *(u16x8*)&Bs[n][kc] = *(const u16x8*)&Bt[(size_t)n * K + k0 + kc];
            }
        }
        __syncthreads();

        bf16x8 a[2];
        #pragma unroll
        for (int mf = 0; mf < 2; ++mf)
            a[mf] = __builtin_bit_cast(bf16x8, *(const u16x8*)&As[wid * 32 + mf * 16 + lm][lk]);
        #pragma unroll
        for (int nf = 0; nf < NF; ++nf) {
            bf16x8 b = __builtin_bit_cast(bf16x8, *(const u16x8*)&Bs[nf * 16 + lm][lk]);
            #pragma unroll
            for (int mf = 0; mf < 2; ++mf)
                acc[mf][nf] = __builtin_amdgcn_mfma_f32_16x16x32_bf16(a[mf], b, acc[mf][nf], 0, 0, 0);
        }
    }

    #pragma unroll
    for (int mf = 0; mf < 2; ++mf)
        #pragma unroll
        for (int nf = 0; nf < NF; ++nf)
            #pragma unroll
            for (int r = 0; r < 4; ++r) {
                const int m = m0 + wid * 32 + mf * 16 + (lane >> 4) * 4 + r;
                if (m < M) C[(size_t)m * N + nf * 16 + lm] = f2bf(acc[mf][nf][r]);
            }
}

// ------------- MFMA GEMM, bf16 A, bf16 out -----------------------------------
template<int K, int N>
__global__ __launch_bounds__(256) void gemm_mfma_bf16a(const unsigned short* __restrict__ A,
                                                       const unsigned short* __restrict__ Bt,
                                                       unsigned short* __restrict__ C, int M)
{
    constexpr int BM = 128, BK = 32, NF = N / 16;
    constexpr int LDW = BK + 8;
    __shared__ unsigned short As[BM][LDW];
    __shared__ unsigned short Bs[N][LDW];

    const int tid  = threadIdx.x;
    const int wid  = tid >> 6;
    const int lane = tid & 63;
    const int lm   = lane & 15;
    const int lk   = (lane >> 4) * 8;
    const int m0   = blockIdx.x * BM;

    f32x4 acc[2][NF] = {};

    for (int k0 = 0; k0 < K; k0 += BK) {
        if (k0) __syncthreads();
        {
            #pragma unroll
            for (int c = 0; c < 2; ++c) {
                const int chunk = tid * 2 + c;     // 512 chunks
                const int r  = chunk >> 2;
                const int kc = (chunk & 3) * 8;
                const int m  = m0 + r;
                u16x8 v = {};
                if (m < M) v = *(const u16x8*)&A[(size_t)m * K + k0 + kc];
                *(u16x8*)&As[r][kc] = v;
            }
        }
        {
            constexpr int CH  = (N * BK / 8) / 256;   // N=64 -> 1
            constexpr int CPR = BK / 8;
            #pragma unroll
            for (int c = 0; c < CH; ++c) {
                const int chunk = tid * CH + c;
                const int n  = chunk / CPR;
                const int kc = (chunk % CPR) * 8;
                *(u16x8*)&Bs[n][kc] = *(const u16x8*)&Bt[(size_t)n * K + k0 + kc];
            }
        }
        __syncthreads();

        bf16x8 a[2];
        #pragma unroll
        for (int mf = 0; mf < 2; ++mf)
            a[mf] = __builtin_bit_cast(bf16x8, *(const u16x8*)&As[wid * 32 + mf * 16 + lm][lk]);
        #pragma unroll
        for (int nf = 0; nf < NF; ++nf) {
            bf16x8 b = __builtin_bit_cast(bf16x8, *(const u16x8*)&Bs[nf * 16 + lm][lk]);
            #pragma unroll
            for (int mf = 0; mf < 2; ++mf)
                acc[mf][nf] = __builtin_amdgcn_mfma_f32_16x16x32_bf16(a[mf], b, acc[mf][nf], 0, 0, 0);
        }
    }

    #pragma unroll
    for (int mf = 0; mf < 2; ++mf)
        #pragma unroll
        for (int nf = 0; nf < NF; ++nf)
            #pragma unroll
            for (int r = 0; r < 4; ++r) {
                const int m = m0 + wid * 32 + mf * 16 + (lane >> 4) * 4 + r;
                if (m < M) C[(size_t)m * N + nf * 16 + lm] = f2bf(acc[mf][nf][r]);
            }
}

// ---------------- CSR build ----------------
__global__ void hist_kernel(const int* __restrict__ er, int* __restrict__ counts)
{
    int e = blockIdx.x * blockDim.x + threadIdx.x;
    if (e < N_EDGES) atomicAdd(&counts[er[e]], 1);
}

__global__ __launch_bounds__(1024) void scan_blocks(const int* __restrict__ counts,
                                                    int* __restrict__ row_ptr,
                                                    int* __restrict__ bsums)
{
    __shared__ int tmp[1024];
    const int tid = threadIdx.x;
    const int gid = blockIdx.x * 1024 + tid;
    const int v = (gid < N_NODES) ? counts[gid] : 0;
    tmp[tid] = v;
    __syncthreads();
    #pragma unroll
    for (int off = 1; off < 1024; off <<= 1) {
        int t = (tid >= off) ? tmp[tid - off] : 0;
        __syncthreads();
        tmp[tid] += t;
        __syncthreads();
    }
    if (gid < N_NODES) row_ptr[gid] = tmp[tid] - v;
    if (tid == 1023) bsums[blockIdx.x] = tmp[1023];
}

__global__ void scan_bsums(int* __restrict__ bsums)
{
    const int lane = threadIdx.x;  // 64 threads
    const int orig = (lane < SCAN_BLOCKS) ? bsums[lane] : 0;
    int v = orig;
    #pragma unroll
    for (int off = 1; off < 64; off <<= 1) {
        int t = __shfl_up(v, off, 64);
        if (lane >= off) v += t;
    }
    if (lane < SCAN_BLOCKS) bsums[lane] = v - orig;  // exclusive
}

__global__ __launch_bounds__(1024) void add_offsets(int* __restrict__ row_ptr,
                                                    const int* __restrict__ bsums)
{
    const int gid = blockIdx.x * 1024 + threadIdx.x;
    if (gid < N_NODES) row_ptr[gid] += bsums[blockIdx.x];
    if (gid == 0) row_ptr[N_NODES] = N_EDGES;
}

// ---- scatter: one packed u64 store per edge; per-row fill counters ----------
__global__ void scatter_cv(const int* __restrict__ er, const int* __restrict__ ec,
                           const float* __restrict__ ev,
                           const int* __restrict__ row_ptr, int* __restrict__ fill,
                           u64* __restrict__ cv)
{
    int e = blockIdx.x * blockDim.x + threadIdx.x;
    if (e >= N_EDGES) return;
    const int r = er[e];
    const int pos = row_ptr[r] + atomicAdd(&fill[r], 1);
    cv[pos] = ((u64)__builtin_bit_cast(unsigned, ev[e]) << 32) | (unsigned)ec[e];
}

// ---- SpMM1: bf16 feat [*,128] gather, fp32 acc, +bias, relu, bf16 out -------
__global__ __launch_bounds__(256) void spmm_bf16_h(const unsigned short* __restrict__ feat,
                                                   const int* __restrict__ row_ptr,
                                                   const u64* __restrict__ cv,
                                                   const float* __restrict__ bias,
                                                   unsigned short* __restrict__ out)
{
    const int wave = blockIdx.x * (blockDim.x >> 6) + (threadIdx.x >> 6);
    const int lane = threadIdx.x & 63;
    if (wave >= N_NODES) return;
    const int beg = row_ptr[wave];
    const int end = row_ptr[wave + 1];

    float ax[4] = {}, ay[4] = {};
    int i = beg;
    for (; i + 3 < end; i += 4) {
        #pragma unroll
        for (int u = 0; u < 4; ++u) {
            const u64 p = cv[i + u];
            const int c = (int)(unsigned)p;
            const float v = __builtin_bit_cast(float, (unsigned)(p >> 32));
            const unsigned w = *(const unsigned*)&feat[(size_t)c * NHID + lane * 2];
            ax[u] += v * bf2f((unsigned short)(w & 0xFFFF));
            ay[u] += v * bf2f((unsigned short)(w >> 16));
        }
    }
    for (; i < end; ++i) {
        const u64 p = cv[i];
        const int c = (int)(unsigned)p;
        const float v = __builtin_bit_cast(float, (unsigned)(p >> 32));
        const unsigned w = *(const unsigned*)&feat[(size_t)c * NHID + lane * 2];
        ax[0] += v * bf2f((unsigned short)(w & 0xFFFF));
        ay[0] += v * bf2f((unsigned short)(w >> 16));
    }
    const float2 bb = *(const float2*)&bias[lane * 2];
    const float rx = fmaxf(ax[0] + ax[1] + ax[2] + ax[3] + bb.x, 0.f);
    const float ry = fmaxf(ay[0] + ay[1] + ay[2] + ay[3] + bb.y, 0.f);
    const unsigned pack = (unsigned)f2bf(rx) | ((unsigned)f2bf(ry) << 16);
    *(unsigned*)&out[(size_t)wave * NHID + lane * 2] = pack;
}

// ---- SpMM2: bf16 feat [*,64] gather, fp32 acc, +bias, fp32 out --------------
__global__ __launch_bounds__(256) void spmm_bf16_o(const unsigned short* __restrict__ feat,
                                                   const int* __restrict__ row_ptr,
                                                   const u64* __restrict__ cv,
                                                   const float* __restrict__ bias,
                                                   float* __restrict__ out)
{
    const int wave = blockIdx.x * (blockDim.x >> 6) + (threadIdx.x >> 6);
    const int lane = threadIdx.x & 63;
    if (wave >= N_NODES) return;
    const int beg = row_ptr[wave];
    const int end = row_ptr[wave + 1];

    float a[4] = {};
    int i = beg;
    for (; i + 3 < end; i += 4) {
        #pragma unroll
        for (int u = 0; u < 4; ++u) {
            const u64 p = cv[i + u];
            const int c = (int)(unsigned)p;
            const float v = __builtin_bit_cast(float, (unsigned)(p >> 32));
            a[u] += v * bf2f(feat[(size_t)c * NCLASS + lane]);
        }
    }
    for (; i < end; ++i) {
        const u64 p = cv[i];
        const int c = (int)(unsigned)p;
        const float v = __builtin_bit_cast(float, (unsigned)(p >> 32));
        a[0] += v * bf2f(feat[(size_t)c * NCLASS + lane]);
    }
    out[(size_t)wave * NCLASS + lane] = a[0] + a[1] + a[2] + a[3] + bias[lane];
}

extern "C" void kernel_launch(void* const* d_in, const int* in_sizes, int n_in,
                              void* d_out, int out_size, void* d_ws, size_t ws_size,
                              hipStream_t stream)
{
    const float* x  = (const float*)d_in[0];
    const float* W1 = (const float*)d_in[1];
    const float* b1 = (const float*)d_in[2];
    const float* W2 = (const float*)d_in[3];
    const float* b2 = (const float*)d_in[4];
    const float* ev = (const float*)d_in[5];
    const int*   er = (const int*)d_in[6];
    const int*   ec = (const int*)d_in[7];
    float* out = (float*)d_out;

    // ---- workspace layout (8B-aligned things first) ----
    u64* cv = (u64*)d_ws;                                    // 800,000 u64
    unsigned short* XW1  = (unsigned short*)(cv + N_EDGES);  // 6,400,000 u16
    unsigned short* Hpre = XW1 + (size_t)N_NODES * NHID;     // 6,400,000 u16
    int* row_ptr = (int*)(Hpre + (size_t)N_NODES * NHID);    // 50016
    int* fill    = row_ptr + 50016;                          // 50016
    int* counts  = fill + 50016;                             // 50016
    int* bsums   = counts + 50016;                           // 64
    unsigned short* W1t = (unsigned short*)(bsums + 64);     // 65536 u16
    unsigned short* W2t = W1t + NFEAT * NHID;                // 8192 u16

    unsigned short* HW2 = XW1;  // [N_NODES, NCLASS] bf16, reuses XW1 slot

    // ---- CSR build ----
    hipMemsetAsync(fill, 0, (50016 * 2 + 64) * sizeof(int), stream);  // fill, counts, bsums
    hist_kernel<<<(N_EDGES + 255) / 256, 256, 0, stream>>>(er, counts);
    scan_blocks<<<SCAN_BLOCKS, 1024, 0, stream>>>(counts, row_ptr, bsums);
    scan_bsums<<<1, 64, 0, stream>>>(bsums);
    add_offsets<<<SCAN_BLOCKS, 1024, 0, stream>>>(row_ptr, bsums);
    scatter_cv<<<(N_EDGES + 255) / 256, 256, 0, stream>>>(er, ec, ev, row_ptr, fill, cv);

    // ---- weight preconvert (bf16, transposed), one launch ----
    {
        const int total = NFEAT * NHID + NHID * NCLASS;
        convert_weights<<<(total + 255) / 256, 256, 0, stream>>>(W1, W2, W1t, W2t);
    }

    // ---- layer 1 ----
    gemm_mfma_f32a<NFEAT, NHID><<<(N_NODES + 127) / 128, 256, 0, stream>>>(x, W1t, XW1, N_NODES);
    spmm_bf16_h<<<(N_NODES + 3) / 4, 256, 0, stream>>>(XW1, row_ptr, cv, b1, Hpre);
    // ---- layer 2 ----
    gemm_mfma_bf16a<NHID, NCLASS><<<(N_NODES + 127) / 128, 256, 0, stream>>>(Hpre, W2t, HW2, N_NODES);
    spmm_bf16_o<<<(N_NODES + 3) / 4, 256, 0, stream>>>(HW2, row_ptr, cv, b2, out);
}